// Round 13
// baseline (219.603 us; speedup 1.0000x reference)
//
#include <hip/hip_runtime.h>
#include <hip/hip_bf16.h>

#define BT 262144
#define BLOCK 256
#define NBLOCKS 1024
#define NIT 4              // BT / (NBLOCKS * 64 rows per block-tile)

typedef __attribute__((ext_vector_type(8))) short short8;
typedef __attribute__((ext_vector_type(4))) float f32x4;
typedef __attribute__((ext_vector_type(4))) unsigned short u16x4;

__device__ __forceinline__ unsigned short f2bf(float f) {
  union { __hip_bfloat16 b; unsigned short u; } v;
  v.b = __float2bfloat16(f);
  return v.u;
}
__device__ __forceinline__ float frcp(float x) { return __builtin_amdgcn_rcpf(x); }
__device__ __forceinline__ float sigm(float x) { return frcp(1.0f + __expf(-x)); }
__device__ __forceinline__ float tanh_(float x) {
  float e = __expf(-2.0f * x);
  return (1.0f - e) * frcp(1.0f + e);
}

// Prep: W_eff = W_ih @ W_in, b_eff = b_ih + b_hh + W_ih @ b_in.
// COLUMN-PERMUTED gate fragments: tile a maps fragment col l16 -> actual
// gate col 4*l16 + (a&3), so each lane owns 4 consecutive output columns
// after the D-layout -> dwordx4 c0 loads and c/h stores.
//   wE  ids [0,16384):      id = ((ks*16 + a)*64 + l)*8 + j
//       n = (a>>2)*64 + 4*(l&15) + (a&3), k = ks*32 + (l>>4)*8 + j
//   wH  ids [16384,32768):  same mapping, value = W_hh[n][k]
//   wO  ids [32768,33792):  (ks*64 + l)*8 + j, n = l&15, k = ks*32+(l>>4)*8+j
//   b_eff ids [33792,34048): floats at byte offset 67584
__global__ void prep_kernel(const float* __restrict__ W_in, const float* __restrict__ b_in,
                            const float* __restrict__ W_ih, const float* __restrict__ W_hh,
                            const float* __restrict__ b_ih, const float* __restrict__ b_hh,
                            const float* __restrict__ W_out,
                            unsigned short* __restrict__ wsW, float* __restrict__ ws_beff) {
  int id = blockIdx.x * blockDim.x + threadIdx.x;
  if (id < 16384) {                       // W_eff fragments
    int j = id & 7, l = (id >> 3) & 63, a = (id >> 9) & 15, ks = id >> 13;
    int n = (a >> 2) * 64 + 4 * (l & 15) + (a & 3);
    int k = ks * 32 + (l >> 4) * 8 + j;
    float s = 0.f;
    #pragma unroll 8
    for (int h = 0; h < 64; ++h) s = fmaf(W_ih[n * 64 + h], W_in[h * 64 + k], s);
    wsW[id] = f2bf(s);
  } else if (id < 32768) {                // W_hh fragments
    int e = id - 16384;
    int j = e & 7, l = (e >> 3) & 63, a = (e >> 9) & 15, ks = (e >> 13) & 1;
    int n = (a >> 2) * 64 + 4 * (l & 15) + (a & 3);
    int k = ks * 32 + (l >> 4) * 8 + j;
    wsW[id] = f2bf(W_hh[n * 64 + k]);
  } else if (id < 33792) {                // W_out fragments (unpermuted)
    int e = id - 32768;
    int j = e & 7, l = (e >> 3) & 63, ks = e >> 9;
    int n = l & 15;
    int k = ks * 32 + (l >> 4) * 8 + j;
    wsW[id] = f2bf(W_out[n * 64 + k]);
  } else if (id < 34048) {                // b_eff
    int n = id - 33792;
    float s = b_ih[n] + b_hh[n];
    #pragma unroll 8
    for (int h = 0; h < 64; ++h) s = fmaf(W_ih[n * 64 + h], b_in[h], s);
    ws_beff[n] = s;
  }
}

__device__ __forceinline__ short8 pack8(float4 lo, float4 hi) {
  short8 r;
  r[0] = (short)f2bf(lo.x); r[1] = (short)f2bf(lo.y);
  r[2] = (short)f2bf(lo.z); r[3] = (short)f2bf(lo.w);
  r[4] = (short)f2bf(hi.x); r[5] = (short)f2bf(hi.y);
  r[6] = (short)f2bf(hi.z); r[7] = (short)f2bf(hi.w);
  return r;
}

// R11 per-wave structure verbatim; LDS trimmed to EXACTLY 40960 B
// (wE 32 KB + hbuf 8 KB) -> 4 blocks/CU = 16 waves/CU (2x R11).
// wH and wO are read from global (L2-resident 66 KB image shared by all
// CUs); beff is a one-time global->register init. launch_bounds(256,4)
// keeps the proven 128-VGPR envelope.
__global__ __launch_bounds__(BLOCK, 4) void lstm_main(
    const float* __restrict__ obs, const float* __restrict__ h0,
    const float* __restrict__ c0, const float* __restrict__ b_out,
    const unsigned short* __restrict__ wsW, const float* __restrict__ ws_beff,
    float* __restrict__ out) {
  __shared__ __attribute__((aligned(16))) unsigned char sbuf[32768];
  __shared__ __attribute__((aligned(16))) unsigned short hbuf[4][1024];
  unsigned short* sw = (unsigned short*)sbuf;

  const int tid = threadIdx.x;
  const int wv = tid >> 6;                 // 0..3
  const int lane = tid & 63;
  const int l16 = lane & 15;
  const int q = lane >> 4;                 // 0..3

  // ---- one-time register init: biases from global ----
  float bias[16];
  #pragma unroll
  for (int a = 0; a < 16; ++a) bias[a] = ws_beff[(a >> 2) * 64 + 4 * l16 + (a & 3)];
  const float boA = b_out[l16];

  // ---- stage wE image -> LDS once (2048 uint4) ----
  for (int i = tid; i < 2048; i += BLOCK)
    ((uint4*)sbuf)[i] = ((const uint4*)wsW)[i];
  __syncthreads();

  const short8* wEv = (const short8*)sw;                 // [2][16][64] LDS
  const short8* wHg = (const short8*)(wsW + 16384);      // [2][16][64] global/L2
  const short8* wOg = (const short8*)(wsW + 32768);      // [2][64]     global/L2
  unsigned short* hb = &hbuf[wv][0];

  float* out_act = out;
  float* out_h = out + (size_t)BT * 16;
  float* out_c = out + (size_t)BT * 80;

  float4 ro[2][4], rh[2][4];

  auto tile_rowbase = [&](int it) -> size_t {
    return ((size_t)(it * NBLOCKS + blockIdx.x)) * 64 + (size_t)wv * 16;
  };
  auto load_oh = [&](int it, int buf) {
    size_t rowbase = tile_rowbase(it);
    const float* po = obs + (rowbase + l16) * 64 + q * 8;
    const float* ph = h0 + (rowbase + l16) * 64 + q * 8;
    ro[buf][0] = *(const float4*)(po);
    ro[buf][1] = *(const float4*)(po + 4);
    ro[buf][2] = *(const float4*)(po + 32);
    ro[buf][3] = *(const float4*)(po + 36);
    rh[buf][0] = *(const float4*)(ph);
    rh[buf][1] = *(const float4*)(ph + 4);
    rh[buf][2] = *(const float4*)(ph + 32);
    rh[buf][3] = *(const float4*)(ph + 36);
  };

  load_oh(0, 0);
  #pragma unroll
  for (int it = 0; it < NIT; ++it) {
    const int cur = it & 1;
    const size_t rowbase = tile_rowbase(it);

    // c0 for current tile: issued now, consumed after the MFMA phase
    f32x4 cold[4];
    #pragma unroll
    for (int r = 0; r < 4; ++r)
      cold[r] = *(const f32x4*)(c0 + (rowbase + (size_t)(4 * q + r)) * 64 + 4 * l16);

    // prefetch next tile's obs/h0 (hidden under this tile's MFMAs)
    if (it + 1 < NIT) load_oh(it + 1, cur ^ 1);

    short8 aObs[2], aH[2];
    aObs[0] = pack8(ro[cur][0], ro[cur][1]);
    aObs[1] = pack8(ro[cur][2], ro[cur][3]);
    aH[0]   = pack8(rh[cur][0], rh[cur][1]);
    aH[1]   = pack8(rh[cur][2], rh[cur][3]);

    f32x4 acc[16];
    #pragma unroll
    for (int a = 0; a < 16; ++a)
      acc[a] = (f32x4){bias[a], bias[a], bias[a], bias[a]};

    #pragma unroll
    for (int ks = 0; ks < 2; ++ks) {
      #pragma unroll
      for (int a = 0; a < 16; ++a) {
        acc[a] = __builtin_amdgcn_mfma_f32_16x16x32_bf16(aObs[ks], wEv[(ks * 16 + a) * 64 + lane], acc[a], 0, 0, 0);
        acc[a] = __builtin_amdgcn_mfma_f32_16x16x32_bf16(aH[ks],  wHg[(ks * 16 + a) * 64 + lane], acc[a], 0, 0, 0);
      }
    }

    // elementwise; D layout: lane holds row 4q+r, cols 4*l16 + t
    #pragma unroll
    for (int r = 0; r < 4; ++r) {
      f32x4 c4, h4;
      u16x4 hb4;
      #pragma unroll
      for (int t = 0; t < 4; ++t) {
        float iv = sigm(acc[t][r]);
        float fv = sigm(acc[4 + t][r]);
        float gv = tanh_(acc[8 + t][r]);
        float ov = sigm(acc[12 + t][r]);
        float cnew = fmaf(fv, cold[r][t], iv * gv);
        float hnew = ov * tanh_(cnew);
        c4[t] = cnew;
        h4[t] = hnew;
        hb4[t] = f2bf(hnew);
      }
      const int hrow = 4 * q + r;
      const size_t m = rowbase + (size_t)hrow;
      __builtin_nontemporal_store(c4, (f32x4*)(out_c + m * 64 + 4 * l16));
      __builtin_nontemporal_store(h4, (f32x4*)(out_h + m * 64 + 4 * l16));
      *(u16x4*)(hb + hrow * 64 + ((4 * l16) ^ ((hrow & 7) << 3))) = hb4;
    }
    // hb is per-wave: same-wave ds_write -> ds_read ordering via lgkmcnt

    // action = tanh(h_new @ W_out^T + b_out); [-1,1] range => identity map
    f32x4 aA = (f32x4){boA, boA, boA, boA};
    short8 a0 = *(const short8*)(hb + l16 * 64 + ((0 * 32 + q * 8) ^ ((l16 & 7) << 3)));
    short8 a1 = *(const short8*)(hb + l16 * 64 + ((1 * 32 + q * 8) ^ ((l16 & 7) << 3)));
    aA = __builtin_amdgcn_mfma_f32_16x16x32_bf16(a0, wOg[lane], aA, 0, 0, 0);
    aA = __builtin_amdgcn_mfma_f32_16x16x32_bf16(a1, wOg[64 + lane], aA, 0, 0, 0);
    #pragma unroll
    for (int r = 0; r < 4; ++r) {
      size_t m = rowbase + (size_t)(4 * q + r);
      __builtin_nontemporal_store(tanh_(aA[r]), out_act + m * 16 + l16);
    }
  }
}

extern "C" void kernel_launch(void* const* d_in, const int* in_sizes, int n_in,
                              void* d_out, int out_size, void* d_ws, size_t ws_size,
                              hipStream_t stream) {
  const float* obs  = (const float*)d_in[0];
  const float* h0   = (const float*)d_in[1];
  const float* c0   = (const float*)d_in[2];
  const float* W_in = (const float*)d_in[3];
  const float* b_in = (const float*)d_in[4];
  const float* W_ih = (const float*)d_in[5];
  const float* W_hh = (const float*)d_in[6];
  const float* b_ih = (const float*)d_in[7];
  const float* b_hh = (const float*)d_in[8];
  const float* W_out = (const float*)d_in[9];
  const float* b_out = (const float*)d_in[10];

  unsigned short* wsW = (unsigned short*)d_ws;
  float* ws_beff = (float*)((char*)d_ws + 67584);

  prep_kernel<<<133, 256, 0, stream>>>(W_in, b_in, W_ih, W_hh, b_ih, b_hh, W_out, wsW, ws_beff);
  lstm_main<<<NBLOCKS, BLOCK, 0, stream>>>(obs, h0, c0, b_out, wsW, ws_beff, (float*)d_out);
}

// Round 14
// 67.218 us; speedup vs baseline: 3.2670x; 3.2670x over previous
//
#include <hip/hip_runtime.h>
#include <hip/hip_bf16.h>

#define BT 262144
#define BLOCK 256
#define NBLOCKS 512
#define NIT 8              // BT / (NBLOCKS * 64 rows per block-tile)

typedef __attribute__((ext_vector_type(8))) short short8;
typedef __attribute__((ext_vector_type(4))) float f32x4;
typedef __attribute__((ext_vector_type(4))) unsigned short u16x4;

__device__ __forceinline__ unsigned short f2bf(float f) {
  union { __hip_bfloat16 b; unsigned short u; } v;
  v.b = __float2bfloat16(f);
  return v.u;
}
__device__ __forceinline__ float frcp(float x) { return __builtin_amdgcn_rcpf(x); }
__device__ __forceinline__ float sigm(float x) { return frcp(1.0f + __expf(-x)); }
__device__ __forceinline__ float tanh_(float x) {
  float e = __expf(-2.0f * x);
  return (1.0f - e) * frcp(1.0f + e);
}

// Prep: W_eff = W_ih @ W_in, b_eff = b_ih + b_hh + W_ih @ b_in.
// COLUMN-PERMUTED gate fragments: tile a maps fragment col l16 -> actual
// gate col 4*l16 + (a&3), so each lane owns 4 consecutive output columns
// after the D-layout -> dwordx4 c0 loads and c/h stores.
//   wE  ids [0,16384):      id = ((ks*16 + a)*64 + l)*8 + j
//       n = (a>>2)*64 + 4*(l&15) + (a&3), k = ks*32 + (l>>4)*8 + j
//   wH  ids [16384,32768):  same mapping, value = W_hh[n][k]
//   wO  ids [32768,33792):  (ks*64 + l)*8 + j, n = l&15, k = ks*32+(l>>4)*8+j
//   b_eff ids [33792,34048): floats at byte offset 67584
__global__ void prep_kernel(const float* __restrict__ W_in, const float* __restrict__ b_in,
                            const float* __restrict__ W_ih, const float* __restrict__ W_hh,
                            const float* __restrict__ b_ih, const float* __restrict__ b_hh,
                            const float* __restrict__ W_out,
                            unsigned short* __restrict__ wsW, float* __restrict__ ws_beff) {
  int id = blockIdx.x * blockDim.x + threadIdx.x;
  if (id < 16384) {                       // W_eff fragments
    int j = id & 7, l = (id >> 3) & 63, a = (id >> 9) & 15, ks = id >> 13;
    int n = (a >> 2) * 64 + 4 * (l & 15) + (a & 3);
    int k = ks * 32 + (l >> 4) * 8 + j;
    float s = 0.f;
    #pragma unroll 8
    for (int h = 0; h < 64; ++h) s = fmaf(W_ih[n * 64 + h], W_in[h * 64 + k], s);
    wsW[id] = f2bf(s);
  } else if (id < 32768) {                // W_hh fragments
    int e = id - 16384;
    int j = e & 7, l = (e >> 3) & 63, a = (e >> 9) & 15, ks = (e >> 13) & 1;
    int n = (a >> 2) * 64 + 4 * (l & 15) + (a & 3);
    int k = ks * 32 + (l >> 4) * 8 + j;
    wsW[id] = f2bf(W_hh[n * 64 + k]);
  } else if (id < 33792) {                // W_out fragments (unpermuted)
    int e = id - 32768;
    int j = e & 7, l = (e >> 3) & 63, ks = e >> 9;
    int n = l & 15;
    int k = ks * 32 + (l >> 4) * 8 + j;
    wsW[id] = f2bf(W_out[n * 64 + k]);
  } else if (id < 34048) {                // b_eff
    int n = id - 33792;
    float s = b_ih[n] + b_hh[n];
    #pragma unroll 8
    for (int h = 0; h < 64; ++h) s = fmaf(W_ih[n * 64 + h], b_in[h], s);
    ws_beff[n] = s;
  }
}

__device__ __forceinline__ short8 pack8(float4 lo, float4 hi) {
  short8 r;
  r[0] = (short)f2bf(lo.x); r[1] = (short)f2bf(lo.y);
  r[2] = (short)f2bf(lo.z); r[3] = (short)f2bf(lo.w);
  r[4] = (short)f2bf(hi.x); r[5] = (short)f2bf(hi.y);
  r[6] = (short)f2bf(hi.z); r[7] = (short)f2bf(hi.w);
  return r;
}

// R11 structure (proven: 128 VGPR, zero scratch, NT stores) with ONE change:
// c0 is now double-buffered and prefetched a FULL iteration ahead (like
// obs/h0), paid for by de-hoisting bias[16] from registers back to LDS
// broadcast reads (net arch-VGPR delta = 0). Occupancy is structurally
// capped at 2 waves/SIMD by the register footprint; this removes the last
// same-iteration load stall instead.
__global__ __launch_bounds__(BLOCK, 2) void lstm_main(
    const float* __restrict__ obs, const float* __restrict__ h0,
    const float* __restrict__ c0, const float* __restrict__ b_out,
    const unsigned short* __restrict__ wsW, const float* __restrict__ ws_beff,
    float* __restrict__ out) {
  __shared__ __attribute__((aligned(16))) unsigned char sbuf[68608];
  __shared__ __attribute__((aligned(16))) unsigned short hbuf[4][1024];
  unsigned short* sw = (unsigned short*)sbuf;

  const int tid = threadIdx.x;
  const int wv = tid >> 6;
  const int lane = tid & 63;
  const int l16 = lane & 15;
  const int q = lane >> 4;                 // 0..3

  // ---- stage full weight image -> LDS once (4288 uint4) ----
  for (int i = tid; i < 4288; i += BLOCK)
    ((uint4*)sbuf)[i] = ((const uint4*)wsW)[i];
  __syncthreads();

  const float* beff_s = (const float*)(sbuf + 67584);   // bias stays in LDS
  const float boA = b_out[l16];

  const short8* wEv = (const short8*)sw;              // [2][16][64]
  const short8* wHv = (const short8*)(sw + 16384);    // [2][16][64]
  const short8* wOv = (const short8*)(sw + 32768);    // [2][64]
  unsigned short* hb = &hbuf[wv][0];

  float* out_act = out;
  float* out_h = out + (size_t)BT * 16;
  float* out_c = out + (size_t)BT * 80;

  float4 ro[2][4], rh[2][4];
  f32x4 cold[2][4];

  auto tile_rowbase = [&](int it) -> size_t {
    return ((size_t)(it * NBLOCKS + blockIdx.x)) * 64 + (size_t)wv * 16;
  };
  auto load_oh = [&](int it, int buf) {
    size_t rowbase = tile_rowbase(it);
    const float* po = obs + (rowbase + l16) * 64 + q * 8;
    const float* ph = h0 + (rowbase + l16) * 64 + q * 8;
    ro[buf][0] = *(const float4*)(po);
    ro[buf][1] = *(const float4*)(po + 4);
    ro[buf][2] = *(const float4*)(po + 32);
    ro[buf][3] = *(const float4*)(po + 36);
    rh[buf][0] = *(const float4*)(ph);
    rh[buf][1] = *(const float4*)(ph + 4);
    rh[buf][2] = *(const float4*)(ph + 32);
    rh[buf][3] = *(const float4*)(ph + 36);
  };
  auto load_c0 = [&](int it, int buf) {
    size_t rowbase = tile_rowbase(it);
    #pragma unroll
    for (int r = 0; r < 4; ++r)
      cold[buf][r] = *(const f32x4*)(c0 + (rowbase + (size_t)(4 * q + r)) * 64 + 4 * l16);
  };

  load_oh(0, 0);
  load_c0(0, 0);
  #pragma unroll
  for (int it = 0; it < NIT; ++it) {
    const int cur = it & 1;
    const size_t rowbase = tile_rowbase(it);

    // prefetch ALL of next tile's inputs (full-iteration lead)
    if (it + 1 < NIT) {
      load_oh(it + 1, cur ^ 1);
      load_c0(it + 1, cur ^ 1);
    }

    short8 aObs[2], aH[2];
    aObs[0] = pack8(ro[cur][0], ro[cur][1]);
    aObs[1] = pack8(ro[cur][2], ro[cur][3]);
    aH[0]   = pack8(rh[cur][0], rh[cur][1]);
    aH[1]   = pack8(rh[cur][2], rh[cur][3]);

    f32x4 acc[16];
    #pragma unroll
    for (int a = 0; a < 16; ++a) {
      float b = beff_s[(a >> 2) * 64 + 4 * l16 + (a & 3)];   // LDS broadcast read
      acc[a] = (f32x4){b, b, b, b};
    }

    #pragma unroll
    for (int ks = 0; ks < 2; ++ks) {
      #pragma unroll
      for (int a = 0; a < 16; ++a) {
        acc[a] = __builtin_amdgcn_mfma_f32_16x16x32_bf16(aObs[ks], wEv[(ks * 16 + a) * 64 + lane], acc[a], 0, 0, 0);
        acc[a] = __builtin_amdgcn_mfma_f32_16x16x32_bf16(aH[ks],  wHv[(ks * 16 + a) * 64 + lane], acc[a], 0, 0, 0);
      }
    }

    // elementwise; D layout: lane holds row 4q+r, cols 4*l16 + t
    #pragma unroll
    for (int r = 0; r < 4; ++r) {
      f32x4 c4, h4;
      u16x4 hb4;
      #pragma unroll
      for (int t = 0; t < 4; ++t) {
        float iv = sigm(acc[t][r]);
        float fv = sigm(acc[4 + t][r]);
        float gv = tanh_(acc[8 + t][r]);
        float ov = sigm(acc[12 + t][r]);
        float cnew = fmaf(fv, cold[cur][r][t], iv * gv);
        float hnew = ov * tanh_(cnew);
        c4[t] = cnew;
        h4[t] = hnew;
        hb4[t] = f2bf(hnew);
      }
      const int hrow = 4 * q + r;
      const size_t m = rowbase + (size_t)hrow;
      __builtin_nontemporal_store(c4, (f32x4*)(out_c + m * 64 + 4 * l16));
      __builtin_nontemporal_store(h4, (f32x4*)(out_h + m * 64 + 4 * l16));
      *(u16x4*)(hb + hrow * 64 + ((4 * l16) ^ ((hrow & 7) << 3))) = hb4;
    }
    // hb is per-wave: same-wave ds_write -> ds_read ordering via lgkmcnt

    // action = tanh(h_new @ W_out^T + b_out); [-1,1] range => identity map
    f32x4 aA = (f32x4){boA, boA, boA, boA};
    #pragma unroll
    for (int ks = 0; ks < 2; ++ks) {
      short8 av = *(const short8*)(hb + l16 * 64 + ((ks * 32 + q * 8) ^ ((l16 & 7) << 3)));
      aA = __builtin_amdgcn_mfma_f32_16x16x32_bf16(av, wOv[ks * 64 + lane], aA, 0, 0, 0);
    }
    #pragma unroll
    for (int r = 0; r < 4; ++r) {
      size_t m = rowbase + (size_t)(4 * q + r);
      __builtin_nontemporal_store(tanh_(aA[r]), out_act + m * 16 + l16);
    }
  }
}

extern "C" void kernel_launch(void* const* d_in, const int* in_sizes, int n_in,
                              void* d_out, int out_size, void* d_ws, size_t ws_size,
                              hipStream_t stream) {
  const float* obs  = (const float*)d_in[0];
  const float* h0   = (const float*)d_in[1];
  const float* c0   = (const float*)d_in[2];
  const float* W_in = (const float*)d_in[3];
  const float* b_in = (const float*)d_in[4];
  const float* W_ih = (const float*)d_in[5];
  const float* W_hh = (const float*)d_in[6];
  const float* b_ih = (const float*)d_in[7];
  const float* b_hh = (const float*)d_in[8];
  const float* W_out = (const float*)d_in[9];
  const float* b_out = (const float*)d_in[10];

  unsigned short* wsW = (unsigned short*)d_ws;
  float* ws_beff = (float*)((char*)d_ws + 67584);

  prep_kernel<<<133, 256, 0, stream>>>(W_in, b_in, W_ih, W_hh, b_ih, b_hh, W_out, wsW, ws_beff);
  lstm_main<<<NBLOCKS, BLOCK, 0, stream>>>(obs, h0, c0, b_out, wsW, ws_beff, (float*)d_out);
}